// Round 3
// baseline (352.968 us; speedup 1.0000x reference)
//
#include <hip/hip_runtime.h>

#define T_DIM 16384
#define B_DIM 64
#define E_DIM 4096
#define NBLK  1024
#define CHUNK 16   // rows per block (T_DIM / NBLK)

typedef float f32x4 __attribute__((ext_vector_type(4)));

// ---------------------------------------------------------------------------
// Single fused kernel, chained-scan (decoupled lookback, aggregates-only).
// Per block of 16 rows:
//   Phase 1: coeff sums (wave per 4 rows, ILP-4 gathers) -> LDS;
//            thread 0: local inclusive scan, publish block aggregate with
//            device-scope release flag.
//   Phase 2: wave 0 polls predecessor flags (<=16 rounds of 64) and composes
//            their aggregates via shuffle scan -> exclusive block prefix.
//   Phase 3: all 256 threads stream 16 output rows (M in 4 float4 regs,
//            nontemporal stores).
// Compose (matches reference, state' = a*state + b):
//   inclusive step: B = a_j*B + b_j (old B); A = a_j*A.
//   compose(P earlier, S later) = (S.a*P.a, S.a*P.b + S.b).
// Deadlock-free: blocks dispatch in increasing id; all 1024 blocks co-resident
// (4 blocks/CU @ 256 thr, VGPR < 128); flags zeroed per replay by memset node.
// ---------------------------------------------------------------------------
__global__ __launch_bounds__(256) void fused_kernel(
    const int*    __restrict__ indices,   // (T, B) int32
    const float*  __restrict__ params,    // (N, 2)
    const float*  __restrict__ M,         // (E,)
    float*        __restrict__ out,       // (T, E)
    float*        __restrict__ aggA,      // ws [NBLK]
    float*        __restrict__ aggB,      // ws [NBLK]
    unsigned int* __restrict__ flags)     // ws [NBLK], pre-zeroed each replay
{
    __shared__ float sA[CHUNK], sB[CHUNK];
    __shared__ float sP[2];
    const int tid   = threadIdx.x;
    const int lane  = tid & 63;
    const int wave  = tid >> 6;          // 0..3
    const int blk   = blockIdx.x;
    const int tbase = blk * CHUNK;

    // ---------------- Phase 1: coeff sums for 16 rows -----------------------
    {
        const float2* __restrict__ P2 = (const float2*)params;
        const int j0 = wave * 4;
        int i0 = indices[((tbase + j0 + 0) << 6) + lane];
        int i1 = indices[((tbase + j0 + 1) << 6) + lane];
        int i2 = indices[((tbase + j0 + 2) << 6) + lane];
        int i3 = indices[((tbase + j0 + 3) << 6) + lane];
        float2 p0 = P2[i0], p1 = P2[i1], p2 = P2[i2], p3 = P2[i3];
        float a0 = p0.x, b0 = p0.y, a1 = p1.x, b1 = p1.y;
        float a2 = p2.x, b2 = p2.y, a3 = p3.x, b3 = p3.y;
        #pragma unroll
        for (int off = 32; off >= 1; off >>= 1) {
            a0 += __shfl_down(a0, off, 64);  b0 += __shfl_down(b0, off, 64);
            a1 += __shfl_down(a1, off, 64);  b1 += __shfl_down(b1, off, 64);
            a2 += __shfl_down(a2, off, 64);  b2 += __shfl_down(b2, off, 64);
            a3 += __shfl_down(a3, off, 64);  b3 += __shfl_down(b3, off, 64);
        }
        if (lane == 0) {
            sA[j0+0] = a0; sB[j0+0] = b0;
            sA[j0+1] = a1; sB[j0+1] = b1;
            sA[j0+2] = a2; sB[j0+2] = b2;
            sA[j0+3] = a3; sB[j0+3] = b3;
        }
    }
    __syncthreads();

    // local inclusive scan + publish aggregate (release)
    if (tid == 0) {
        float a = 1.0f, b = 0.0f;
        #pragma unroll
        for (int j = 0; j < CHUNK; ++j) {
            float aj = sA[j], bj = sB[j];
            b = aj * b + bj;             // uses old b only
            a = aj * a;
            sA[j] = a; sB[j] = b;
        }
        __hip_atomic_store(&aggA[blk], a, __ATOMIC_RELAXED, __HIP_MEMORY_SCOPE_AGENT);
        __hip_atomic_store(&aggB[blk], b, __ATOMIC_RELAXED, __HIP_MEMORY_SCOPE_AGENT);
        __hip_atomic_store(&flags[blk], 1u, __ATOMIC_RELEASE, __HIP_MEMORY_SCOPE_AGENT);
    }

    // load M into registers now: 16 KB broadcast, overlaps with lookback
    const f32x4* __restrict__ M4 = (const f32x4*)M;
    f32x4 m0 = M4[tid], m1 = M4[tid + 256], m2 = M4[tid + 512], m3 = M4[tid + 768];

    // ---------------- Phase 2: lookback over predecessor aggregates ---------
    if (wave == 0) {
        float Pa = 1.0f, Pb = 0.0f;
        const int npred   = blk;
        const int nrounds = (npred + 63) >> 6;
        for (int r = 0; r < nrounds; ++r) {
            const int  idx = (r << 6) + lane;
            const bool act = idx < npred;
            const unsigned long long need = __ballot(act);
            for (;;) {
                unsigned int f = act
                    ? __hip_atomic_load(&flags[idx], __ATOMIC_ACQUIRE, __HIP_MEMORY_SCOPE_AGENT)
                    : 1u;
                unsigned long long got = __ballot(f != 0u);
                if ((got & need) == need) break;
                __builtin_amdgcn_s_sleep(1);
            }
            float a = act ? __hip_atomic_load(&aggA[idx], __ATOMIC_RELAXED, __HIP_MEMORY_SCOPE_AGENT) : 1.0f;
            float b = act ? __hip_atomic_load(&aggB[idx], __ATOMIC_RELAXED, __HIP_MEMORY_SCOPE_AGENT) : 0.0f;
            // inclusive shuffle scan across the 64-lane segment
            #pragma unroll
            for (int off = 1; off < 64; off <<= 1) {
                float pa = __shfl_up(a, off, 64);
                float pb = __shfl_up(b, off, 64);
                if (lane >= off) {
                    float nb = a * pb + b;   // uses OLD a
                    a = a * pa;
                    b = nb;
                }
            }
            const float Sa = __shfl(a, 63, 64);
            const float Sb = __shfl(b, 63, 64);
            const float nPb = Sa * Pb + Sb;  // compose(P earlier, S later)
            Pa = Sa * Pa;
            Pb = nPb;
        }
        if (lane == 0) { sP[0] = Pa; sP[1] = Pb; }
    }
    __syncthreads();

    // ---------------- Phase 3: apply prefix, stream 16 output rows ----------
    const float Pa = sP[0], Pb = sP[1];
    #pragma unroll
    for (int j = 0; j < CHUNK; ++j) {
        const float la = sA[j], lb = sB[j];
        const float At = la * Pa;
        const float Bt = la * Pb + lb;
        f32x4* __restrict__ O4 = (f32x4*)(out + (size_t)(tbase + j) * E_DIM);
        f32x4 r;
        r = At * m0 + Bt;  __builtin_nontemporal_store(r, &O4[tid      ]);
        r = At * m1 + Bt;  __builtin_nontemporal_store(r, &O4[tid + 256]);
        r = At * m2 + Bt;  __builtin_nontemporal_store(r, &O4[tid + 512]);
        r = At * m3 + Bt;  __builtin_nontemporal_store(r, &O4[tid + 768]);
    }
}

extern "C" void kernel_launch(void* const* d_in, const int* in_sizes, int n_in,
                              void* d_out, int out_size, void* d_ws, size_t ws_size,
                              hipStream_t stream) {
    const int*   indices = (const int*)d_in[0];     // (T, B) int32 on device
    const float* M_prev  = (const float*)d_in[1];   // (E,)
    const float* params  = (const float*)d_in[2];   // (N, 2)
    float* out = (float*)d_out;

    float*        aggA  = (float*)d_ws;             // [NBLK]
    float*        aggB  = aggA + NBLK;              // [NBLK]
    unsigned int* flags = (unsigned int*)(aggB + NBLK); // [NBLK]

    // re-zero flags every replay (ws is poisoned by the harness each iteration)
    hipMemsetAsync(flags, 0, NBLK * sizeof(unsigned int), stream);

    fused_kernel<<<NBLK, 256, 0, stream>>>(indices, params, M_prev, out,
                                           aggA, aggB, flags);
}